// Round 6
// baseline (354.204 us; speedup 1.0000x reference)
//
#include <hip/hip_runtime.h>
#include <hip/hip_bf16.h>

typedef __hip_bfloat16 bf16;
typedef short v8s __attribute__((ext_vector_type(8)));
typedef float v4f __attribute__((ext_vector_type(4)));

#define BFLO(u) __uint_as_float((u) << 16)
#define BFHI(u) __uint_as_float((u) & 0xffff0000u)

#define CH 8192        // edges per count/distribute block
#define MAXNB 800      // >= 2 * ceil(N/256) = 782

// Derive index stride in-block: int64 LE with values < 2^31 has zero odd slots.
__device__ __forceinline__ int block_stride(const int* e0, int E, int* sm) {
    int t = threadIdx.x;
    if (t == 0) *sm = 0;
    __syncthreads();
    int nz = 0;
    for (int i = t; i < 2048; i += 256) {
        int slot = 2 * i + 1;
        if (slot < 2 * E) nz |= (e0[slot] != 0);
    }
    if (nz) atomicOr(sm, 1);
    __syncthreads();
    return *sm ? 1 : 2;
}

// ---------------- cvt (x fp32 -> Abig cols 256:383 bf16) + weight prep fused ----------------

__global__ __launch_bounds__(256) void cvtprep_kernel(const float4* __restrict__ x4,
                                                      uint2* __restrict__ Ab,
                                                      const float* __restrict__ Wrel,
                                                      const float* __restrict__ Wself,
                                                      const float* __restrict__ convw,
                                                      const float* __restrict__ convb,
                                                      bf16* __restrict__ B1T,
                                                      bf16* __restrict__ B2T,
                                                      float* __restrict__ cbf,
                                                      int N, int cvtBlocks) {
    if ((int)blockIdx.x < cvtBlocks) {
        int i = blockIdx.x * 256 + threadIdx.x;
        if (i >= N * 32) return;
        int n = i >> 5, g = i & 31;
        float4 f = x4[i];
        union { uint2 u; bf16 h[4]; } o;
        o.h[0] = __float2bfloat16(f.x); o.h[1] = __float2bfloat16(f.y);
        o.h[2] = __float2bfloat16(f.z); o.h[3] = __float2bfloat16(f.w);
        Ab[(size_t)n * 96 + 64 + g] = o.u;
    } else {
        int i = (blockIdx.x - cvtBlocks) * 256 + threadIdx.x;
        if (i < 49152) {
            int co = i / 384, k = i % 384;
            float v;
            if (k < 128)      v = Wrel[co * 128 + k];
            else if (k < 256) v = Wrel[16384 + co * 128 + (k - 128)];
            else              v = Wself[co * 128 + (k - 256)];
            B1T[i] = __float2bfloat16(v);
        } else if (i < 98304) {
            int j = i - 49152;
            int co = j / 384, k = j % 384, kk = k >> 7, ci = k & 127;
            B2T[j] = __float2bfloat16(convw[co * 384 + ci * 3 + kk]);
        } else if (i < 98432) {
            int c = i - 98304;
            cbf[c] = convb[c];
        }
    }
}

// ---------------- bucket count: bucket = r*nbrr + (tgt>>8) ----------------

__global__ __launch_bounds__(256) void count_kernel(const int* __restrict__ e0,
                                                    const int* __restrict__ e1,
                                                    int* __restrict__ gcnt, int E, int nbrr) {
    __shared__ int hist[MAXNB];
    __shared__ int smf;
    int st = block_stride(e0, E, &smf);
    int NB = 2 * nbrr;
    int t = threadIdx.x;
    for (int i = t; i < NB; i += 256) hist[i] = 0;
    __syncthreads();
    long base = (long)blockIdx.x * CH;
#pragma unroll
    for (int j = 0; j < CH / 256; ++j) {
        long e = base + j * 256 + t;
        if (e < 2 * (long)E) {
            int r = e >= E;
            long idx = r ? e - E : e;
            int tgt = (r ? e1 : e0)[(size_t)(E + idx) * st];
            atomicAdd(&hist[r * nbrr + (tgt >> 8)], 1);
        }
    }
    __syncthreads();
    for (int i = t; i < NB; i += 256) if (hist[i]) atomicAdd(&gcnt[i], hist[i]);
}

// ---------------- exclusive scan of bucket counts (single block) ----------------

__global__ __launch_bounds__(256) void bscan_kernel(const int* __restrict__ gcnt,
                                                    int* __restrict__ gbase,
                                                    int* __restrict__ gcur, int NB) {
    __shared__ int tsum[256];
    int t = threadIdx.x;
    int v[4]; int s = 0;
#pragma unroll
    for (int j = 0; j < 4; ++j) { int i = t * 4 + j; v[j] = (i < NB) ? gcnt[i] : 0; s += v[j]; }
    tsum[t] = s; __syncthreads();
    for (int d = 1; d < 256; d <<= 1) {
        int add = (t >= d) ? tsum[t - d] : 0;
        __syncthreads(); tsum[t] += add; __syncthreads();
    }
    int run = tsum[t] - s;
#pragma unroll
    for (int j = 0; j < 4; ++j) {
        int i = t * 4 + j;
        if (i < NB) { gbase[i] = run; gcur[i] = run; }
        run += v[j];
    }
    if (t == 255) gbase[NB] = run;
}

// ---------------- distribute: LDS-sorted runs -> contiguous bucket segments ----------------
// record = src (17b) | tgt_local (8b) << 17

__global__ __launch_bounds__(256) void dist_kernel(const int* __restrict__ e0,
                                                   const int* __restrict__ e1,
                                                   int* __restrict__ gcur,
                                                   unsigned int* __restrict__ esorted,
                                                   int E, int nbrr) {
    __shared__ int hist[MAXNB], lstart[MAXNB], lcur[MAXNB], runbase[MAXNB];
    __shared__ unsigned int ordered[CH];
    __shared__ int tsum[256];
    __shared__ int smf;
    int st = block_stride(e0, E, &smf);
    int NB = 2 * nbrr;
    int t = threadIdx.x;
    for (int i = t; i < NB; i += 256) { hist[i] = 0; lcur[i] = 0; }
    __syncthreads();
    long base = (long)blockIdx.x * CH;
    unsigned int rec[CH / 256]; short bk[CH / 256];
#pragma unroll
    for (int j = 0; j < CH / 256; ++j) {
        long e = base + j * 256 + t;
        if (e < 2 * (long)E) {
            int r = e >= E;
            long idx = r ? e - E : e;
            const int* ei = r ? e1 : e0;
            int src = ei[(size_t)idx * st];
            int tgt = ei[(size_t)(E + idx) * st];
            bk[j] = (short)(r * nbrr + (tgt >> 8));
            rec[j] = (unsigned int)src | ((unsigned int)(tgt & 255) << 17);
            atomicAdd(&hist[bk[j]], 1);
        } else bk[j] = -1;
    }
    __syncthreads();
    {   // block-level exclusive scan of hist -> lstart
        int vv[4]; int s = 0;
#pragma unroll
        for (int j = 0; j < 4; ++j) { int i = t * 4 + j; vv[j] = (i < NB) ? hist[i] : 0; s += vv[j]; }
        tsum[t] = s; __syncthreads();
        for (int d = 1; d < 256; d <<= 1) {
            int add = (t >= d) ? tsum[t - d] : 0;
            __syncthreads(); tsum[t] += add; __syncthreads();
        }
        int run = tsum[t] - s;
#pragma unroll
        for (int j = 0; j < 4; ++j) { int i = t * 4 + j; if (i < NB) { lstart[i] = run; run += vv[j]; } }
    }
    __syncthreads();
    // reserve global run per touched bucket
    for (int i = t; i < NB; i += 256) if (hist[i]) runbase[i] = atomicAdd(&gcur[i], hist[i]);
    __syncthreads();
    // scatter records into bucket-ordered staging
#pragma unroll
    for (int j = 0; j < CH / 256; ++j) if (bk[j] >= 0) {
        int p = lstart[bk[j]] + atomicAdd(&lcur[bk[j]], 1);
        ordered[p] = rec[j];
    }
    __syncthreads();
    // copy runs to global: wave-per-bucket, lane-parallel within run
    int w = t >> 6, lane = t & 63;
    for (int b = w; b < NB; b += 4) {
        int n = hist[b];
        if (n) {
            int gp = runbase[b], lp = lstart[b];
            for (int q = lane; q < n; q += 64) esorted[gp + q] = ordered[lp + q];
        }
    }
}

// ---------------- fused per-bucket CSR + gather ----------------
// One block per bucket (256 nodes of one relation). Phase 1: LDS hist/scan,
// node-sorted scatter of the segment into esrc (block-local writes). Phase 2:
// one half-wave per node streams its contiguous edge list, unroll-8 MLP row
// loads, fp32 accumulate, bf16 writeback into Abig cols r*128..

__global__ __launch_bounds__(256) void csrgather_kernel(const unsigned int* __restrict__ esorted,
                                                        const int* __restrict__ gbase,
                                                        int* __restrict__ esrc,
                                                        uint2* __restrict__ Ab,
                                                        int N, int nbrr) {
    __shared__ int hist[256], nstart[256], lcur[256], tsum[256];
    int b = blockIdx.x;
    int r = b >= nbrr;
    int g = r ? b - nbrr : b;
    int t = threadIdx.x;
    int s0 = gbase[b], s1 = gbase[b + 1];
    hist[t] = 0;
    __syncthreads();
    for (int i = s0 + t; i < s1; i += 256)
        atomicAdd(&hist[(esorted[i] >> 17) & 255], 1);
    __syncthreads();
    int h = hist[t];
    tsum[t] = h; __syncthreads();
    for (int d = 1; d < 256; d <<= 1) {
        int add = (t >= d) ? tsum[t - d] : 0;
        __syncthreads(); tsum[t] += add; __syncthreads();
    }
    int start = tsum[t] - h;   // exclusive
    nstart[t] = start;
    lcur[t] = start;
    __syncthreads();
    for (int i = s0 + t; i < s1; i += 256) {
        unsigned int rec = esorted[i];
        int tl = (rec >> 17) & 255;
        int p = atomicAdd(&lcur[tl], 1);
        esrc[s0 + p] = rec & 0x1FFFF;
    }
    __syncthreads();   // drains vmem: block's esrc writes visible to its reads

    int hw = t >> 5, lj = t & 31;
    for (int nl = hw; nl < 256; nl += 8) {
        int n = g * 256 + nl;
        if (n >= N) continue;
        int c = hist[nl];
        int sbase = s0 + nstart[nl];
        float a0 = 0.f, a1 = 0.f, a2 = 0.f, a3 = 0.f;
        for (int i0 = 0; i0 < c; i0 += 8) {
            int cm1 = c - 1;
            int s[8]; uint2 v[8];
#pragma unroll
            for (int u = 0; u < 8; ++u) {
                int j = i0 + u; j = (j <= cm1) ? j : cm1;
                s[u] = esrc[sbase + j];
            }
#pragma unroll
            for (int u = 0; u < 8; ++u)
                v[u] = Ab[(size_t)s[u] * 96 + 64 + lj];
#pragma unroll
            for (int u = 0; u < 8; ++u) {
                if (i0 + u < c) {
                    a0 += BFLO(v[u].x); a1 += BFHI(v[u].x);
                    a2 += BFLO(v[u].y); a3 += BFHI(v[u].y);
                }
            }
        }
        union { uint2 u; bf16 hh[4]; } o;
        o.hh[0] = __float2bfloat16(a0); o.hh[1] = __float2bfloat16(a1);
        o.hh[2] = __float2bfloat16(a2); o.hh[3] = __float2bfloat16(a3);
        Ab[(size_t)n * 96 + (size_t)r * 32 + lj] = o.u;
    }
}

// ---------------- GEMM1: agg[M,128](bf16) = Abig @ B1T^T,  K = 384 ----------------

__global__ __launch_bounds__(256) void gemm1_kernel(const bf16* __restrict__ Ab,
                                                    const bf16* __restrict__ B1T,
                                                    bf16* __restrict__ agg, int M) {
    __shared__ bf16 Al[128 * 72];
    __shared__ bf16 Bl[128 * 72];
    int t = threadIdx.x;
    int lane = t & 63, wv = t >> 6, wm = wv >> 1, wn = wv & 1;
    int m0 = blockIdx.x * 128;
    v4f acc[4][4] = {};
    for (int kt = 0; kt < 6; ++kt) {
        int k0 = kt * 64;
#pragma unroll
        for (int i = 0; i < 4; ++i) {
            int q = i * 256 + t;
            int row = q >> 3, ch = q & 7;
            int grow = m0 + row;
            int4 va = {0, 0, 0, 0};
            if (grow < M) va = *(const int4*)(Ab + (size_t)grow * 384 + k0 + ch * 8);
            *(int4*)&Al[row * 72 + ch * 8] = va;
            *(int4*)&Bl[row * 72 + ch * 8] = *(const int4*)(B1T + row * 384 + k0 + ch * 8);
        }
        __syncthreads();
        int r = lane & 15, qq = lane >> 4;
#pragma unroll
        for (int ks = 0; ks < 2; ++ks) {
            v8s af[4], bfr[4];
#pragma unroll
            for (int tm = 0; tm < 4; ++tm)
                af[tm] = *(const v8s*)&Al[(wm * 64 + tm * 16 + r) * 72 + ks * 32 + qq * 8];
#pragma unroll
            for (int tn = 0; tn < 4; ++tn)
                bfr[tn] = *(const v8s*)&Bl[(wn * 64 + tn * 16 + r) * 72 + ks * 32 + qq * 8];
#pragma unroll
            for (int tm = 0; tm < 4; ++tm)
#pragma unroll
                for (int tn = 0; tn < 4; ++tn)
                    acc[tm][tn] = __builtin_amdgcn_mfma_f32_16x16x32_bf16(af[tm], bfr[tn], acc[tm][tn], 0, 0, 0);
        }
        __syncthreads();
    }
    int r = lane & 15, qq = lane >> 4;
#pragma unroll
    for (int tm = 0; tm < 4; ++tm)
#pragma unroll
        for (int tn = 0; tn < 4; ++tn)
#pragma unroll
            for (int reg = 0; reg < 4; ++reg) {
                int grow = m0 + wm * 64 + tm * 16 + qq * 4 + reg;
                if (grow < M) {
                    int col = wn * 64 + tn * 16 + r;
                    agg[(size_t)grow * 128 + col] = __float2bfloat16(acc[tm][tn][reg]);
                }
            }
}

// ---------------- GEMM2: out[n](fp32) = relu(b + sum_kk agg[n+kk-1] @ Wkk^T),  K = 384 ----------------

__global__ __launch_bounds__(256) void gemm2_kernel(const bf16* __restrict__ agg,
                                                    const bf16* __restrict__ B2T,
                                                    const float* __restrict__ cbf,
                                                    float* __restrict__ out, int M) {
    __shared__ bf16 Al[128 * 72];
    __shared__ bf16 Bl[128 * 72];
    int t = threadIdx.x;
    int lane = t & 63, wv = t >> 6, wm = wv >> 1, wn = wv & 1;
    int m0 = blockIdx.x * 128;
    v4f acc[4][4] = {};
    for (int kt = 0; kt < 6; ++kt) {
        int k0 = kt * 64;
        int kk = k0 >> 7;          // which conv tap (0..2)
        int rem = k0 & 127;        // ci offset within tap
#pragma unroll
        for (int i = 0; i < 4; ++i) {
            int q = i * 256 + t;
            int row = q >> 3, ch = q & 7;
            int srow = m0 + row + kk - 1;
            int4 va = {0, 0, 0, 0};
            if (srow >= 0 && srow < M) {
                va = *(const int4*)(agg + (size_t)srow * 128 + rem + ch * 8);
            }
            *(int4*)&Al[row * 72 + ch * 8] = va;
            *(int4*)&Bl[row * 72 + ch * 8] = *(const int4*)(B2T + row * 384 + k0 + ch * 8);
        }
        __syncthreads();
        int r = lane & 15, qq = lane >> 4;
#pragma unroll
        for (int ks = 0; ks < 2; ++ks) {
            v8s af[4], bfr[4];
#pragma unroll
            for (int tm = 0; tm < 4; ++tm)
                af[tm] = *(const v8s*)&Al[(wm * 64 + tm * 16 + r) * 72 + ks * 32 + qq * 8];
#pragma unroll
            for (int tn = 0; tn < 4; ++tn)
                bfr[tn] = *(const v8s*)&Bl[(wn * 64 + tn * 16 + r) * 72 + ks * 32 + qq * 8];
#pragma unroll
            for (int tm = 0; tm < 4; ++tm)
#pragma unroll
                for (int tn = 0; tn < 4; ++tn)
                    acc[tm][tn] = __builtin_amdgcn_mfma_f32_16x16x32_bf16(af[tm], bfr[tn], acc[tm][tn], 0, 0, 0);
        }
        __syncthreads();
    }
    int r = lane & 15, qq = lane >> 4;
#pragma unroll
    for (int tm = 0; tm < 4; ++tm)
#pragma unroll
        for (int tn = 0; tn < 4; ++tn) {
            int col = wn * 64 + tn * 16 + r;
            float bias = cbf[col];
#pragma unroll
            for (int reg = 0; reg < 4; ++reg) {
                int grow = m0 + wm * 64 + tm * 16 + qq * 4 + reg;
                if (grow < M) {
                    float v = acc[tm][tn][reg] + bias;
                    out[(size_t)grow * 128 + col] = fmaxf(v, 0.f);
                }
            }
        }
}

// ---------------- launch ----------------

extern "C" void kernel_launch(void* const* d_in, const int* in_sizes, int n_in,
                              void* d_out, int out_size, void* d_ws, size_t ws_size,
                              hipStream_t stream) {
    const float* x     = (const float*)d_in[0];
    const int*   e0    = (const int*)d_in[1];
    const int*   e1    = (const int*)d_in[2];
    const float* Wrel  = (const float*)d_in[3];
    const float* Wself = (const float*)d_in[4];
    const float* convw = (const float*)d_in[5];
    const float* convb = (const float*)d_in[6];
    float* out = (float*)d_out;

    int N = in_sizes[0] / 128;   // 100000
    int E = in_sizes[1] / 2;     // 600000
    int nbrr = (N + 255) >> 8;   // 391 buckets per relation
    int NB = 2 * nbrr;           // 782

    char* p = (char*)d_ws;
    auto alloc = [&](size_t bytes) { char* q = p; p += (bytes + 255) & ~(size_t)255; return q; };
    int*  gcnt  = (int*)alloc((size_t)MAXNB * 4);
    int*  gbase = (int*)alloc((size_t)(MAXNB + 1) * 4);
    int*  gcur  = (int*)alloc((size_t)MAXNB * 4);
    unsigned int* esorted = (unsigned int*)alloc((size_t)2 * E * 4);
    int*  esrc  = (int*)alloc((size_t)2 * E * 4);
    bf16* Ab   = (bf16*)alloc((size_t)N * 384 * 2);   // [H0 | H1 | x_bf16]
    bf16* agg  = (bf16*)alloc((size_t)N * 128 * 2);
    bf16* B1T  = (bf16*)alloc(384 * 128 * 2);
    bf16* B2T  = (bf16*)alloc(384 * 128 * 2);
    float* cbf = (float*)alloc(512);

    hipMemsetAsync(gcnt, 0, (size_t)NB * 4, stream);

    int cvtBlocks = (N * 32 + 255) / 256;
    int prepBlocks = (98432 + 255) / 256;
    cvtprep_kernel<<<cvtBlocks + prepBlocks, 256, 0, stream>>>((const float4*)x, (uint2*)Ab,
                                                               Wrel, Wself, convw, convb,
                                                               B1T, B2T, cbf, N, cvtBlocks);

    int chBlocks = (2 * E + CH - 1) / CH;    // 147
    count_kernel<<<chBlocks, 256, 0, stream>>>(e0, e1, gcnt, E, nbrr);
    bscan_kernel<<<1, 256, 0, stream>>>(gcnt, gbase, gcur, NB);
    dist_kernel<<<chBlocks, 256, 0, stream>>>(e0, e1, gcur, esorted, E, nbrr);

    csrgather_kernel<<<NB, 256, 0, stream>>>(esorted, gbase, esrc, (uint2*)Ab, N, nbrr);

    int mBlocks = (N + 127) / 128;
    gemm1_kernel<<<mBlocks, 256, 0, stream>>>(Ab, B1T, agg, N);
    gemm2_kernel<<<mBlocks, 256, 0, stream>>>(agg, B2T, cbf, out, N);
}

// Round 7
// 333.040 us; speedup vs baseline: 1.0636x; 1.0636x over previous
//
#include <hip/hip_runtime.h>
#include <hip/hip_bf16.h>

typedef __hip_bfloat16 bf16;
typedef short v8s __attribute__((ext_vector_type(8)));
typedef float v4f __attribute__((ext_vector_type(4)));

#define BFLO(u) __uint_as_float((u) << 16)
#define BFHI(u) __uint_as_float((u) & 0xffff0000u)

#define CH 8192        // edges per count/distribute block
#define MAXNB 800      // >= 2 * ceil(N/256) = 782

// Derive index stride in-block: int64 LE with values < 2^31 has zero odd slots.
__device__ __forceinline__ int block_stride(const int* e0, int E, int* sm) {
    int t = threadIdx.x;
    if (t == 0) *sm = 0;
    __syncthreads();
    int nz = 0;
    for (int i = t; i < 2048; i += 256) {
        int slot = 2 * i + 1;
        if (slot < 2 * E) nz |= (e0[slot] != 0);
    }
    if (nz) atomicOr(sm, 1);
    __syncthreads();
    return *sm ? 1 : 2;
}

// ---------------- cvt (x fp32 -> Abig cols 256:383 bf16) + weight prep fused ----------------

__global__ __launch_bounds__(256) void cvtprep_kernel(const float4* __restrict__ x4,
                                                      uint2* __restrict__ Ab,
                                                      const float* __restrict__ Wrel,
                                                      const float* __restrict__ Wself,
                                                      const float* __restrict__ convw,
                                                      const float* __restrict__ convb,
                                                      bf16* __restrict__ B1T,
                                                      bf16* __restrict__ B2T,
                                                      float* __restrict__ cbf,
                                                      int N, int cvtBlocks) {
    if ((int)blockIdx.x < cvtBlocks) {
        int i = blockIdx.x * 256 + threadIdx.x;
        if (i >= N * 32) return;
        int n = i >> 5, g = i & 31;
        float4 f = x4[i];
        union { uint2 u; bf16 h[4]; } o;
        o.h[0] = __float2bfloat16(f.x); o.h[1] = __float2bfloat16(f.y);
        o.h[2] = __float2bfloat16(f.z); o.h[3] = __float2bfloat16(f.w);
        Ab[(size_t)n * 96 + 64 + g] = o.u;
    } else {
        int i = (blockIdx.x - cvtBlocks) * 256 + threadIdx.x;
        if (i < 49152) {
            int co = i / 384, k = i % 384;
            float v;
            if (k < 128)      v = Wrel[co * 128 + k];
            else if (k < 256) v = Wrel[16384 + co * 128 + (k - 128)];
            else              v = Wself[co * 128 + (k - 256)];
            B1T[i] = __float2bfloat16(v);
        } else if (i < 98304) {
            int j = i - 49152;
            int co = j / 384, k = j % 384, kk = k >> 7, ci = k & 127;
            B2T[j] = __float2bfloat16(convw[co * 384 + ci * 3 + kk]);
        } else if (i < 98432) {
            int c = i - 98304;
            cbf[c] = convb[c];
        }
    }
}

// ---------------- bucket count: bucket = r*nbrr + (tgt>>8) ----------------

__global__ __launch_bounds__(256) void count_kernel(const int* __restrict__ e0,
                                                    const int* __restrict__ e1,
                                                    int* __restrict__ gcnt, int E, int nbrr) {
    __shared__ int hist[MAXNB];
    __shared__ int smf;
    int st = block_stride(e0, E, &smf);
    int NB = 2 * nbrr;
    int t = threadIdx.x;
    for (int i = t; i < NB; i += 256) hist[i] = 0;
    __syncthreads();
    long base = (long)blockIdx.x * CH;
#pragma unroll
    for (int j = 0; j < CH / 256; ++j) {
        long e = base + j * 256 + t;
        if (e < 2 * (long)E) {
            int r = e >= E;
            long idx = r ? e - E : e;
            int tgt = (r ? e1 : e0)[(size_t)(E + idx) * st];
            atomicAdd(&hist[r * nbrr + (tgt >> 8)], 1);
        }
    }
    __syncthreads();
    for (int i = t; i < NB; i += 256) if (hist[i]) atomicAdd(&gcnt[i], hist[i]);
}

// ---------------- exclusive scan of bucket counts (single block) ----------------

__global__ __launch_bounds__(256) void bscan_kernel(const int* __restrict__ gcnt,
                                                    int* __restrict__ gbase,
                                                    int* __restrict__ gcur, int NB) {
    __shared__ int tsum[256];
    int t = threadIdx.x;
    int v[4]; int s = 0;
#pragma unroll
    for (int j = 0; j < 4; ++j) { int i = t * 4 + j; v[j] = (i < NB) ? gcnt[i] : 0; s += v[j]; }
    tsum[t] = s; __syncthreads();
    for (int d = 1; d < 256; d <<= 1) {
        int add = (t >= d) ? tsum[t - d] : 0;
        __syncthreads(); tsum[t] += add; __syncthreads();
    }
    int run = tsum[t] - s;
#pragma unroll
    for (int j = 0; j < 4; ++j) {
        int i = t * 4 + j;
        if (i < NB) { gbase[i] = run; gcur[i] = run; }
        run += v[j];
    }
    if (t == 255) gbase[NB] = run;
}

// ---------------- distribute: LDS-sorted runs -> contiguous bucket segments ----------------
// record = src (17b) | tgt_local (8b) << 17

__global__ __launch_bounds__(256) void dist_kernel(const int* __restrict__ e0,
                                                   const int* __restrict__ e1,
                                                   int* __restrict__ gcur,
                                                   unsigned int* __restrict__ esorted,
                                                   int E, int nbrr) {
    __shared__ int hist[MAXNB], lstart[MAXNB], lcur[MAXNB], runbase[MAXNB];
    __shared__ unsigned int ordered[CH];
    __shared__ int tsum[256];
    __shared__ int smf;
    int st = block_stride(e0, E, &smf);
    int NB = 2 * nbrr;
    int t = threadIdx.x;
    for (int i = t; i < NB; i += 256) { hist[i] = 0; lcur[i] = 0; }
    __syncthreads();
    long base = (long)blockIdx.x * CH;
    unsigned int rec[CH / 256]; short bk[CH / 256];
#pragma unroll
    for (int j = 0; j < CH / 256; ++j) {
        long e = base + j * 256 + t;
        if (e < 2 * (long)E) {
            int r = e >= E;
            long idx = r ? e - E : e;
            const int* ei = r ? e1 : e0;
            int src = ei[(size_t)idx * st];
            int tgt = ei[(size_t)(E + idx) * st];
            bk[j] = (short)(r * nbrr + (tgt >> 8));
            rec[j] = (unsigned int)src | ((unsigned int)(tgt & 255) << 17);
            atomicAdd(&hist[bk[j]], 1);
        } else bk[j] = -1;
    }
    __syncthreads();
    {   // block-level exclusive scan of hist -> lstart
        int vv[4]; int s = 0;
#pragma unroll
        for (int j = 0; j < 4; ++j) { int i = t * 4 + j; vv[j] = (i < NB) ? hist[i] : 0; s += vv[j]; }
        tsum[t] = s; __syncthreads();
        for (int d = 1; d < 256; d <<= 1) {
            int add = (t >= d) ? tsum[t - d] : 0;
            __syncthreads(); tsum[t] += add; __syncthreads();
        }
        int run = tsum[t] - s;
#pragma unroll
        for (int j = 0; j < 4; ++j) { int i = t * 4 + j; if (i < NB) { lstart[i] = run; run += vv[j]; } }
    }
    __syncthreads();
    // reserve global run per touched bucket
    for (int i = t; i < NB; i += 256) if (hist[i]) runbase[i] = atomicAdd(&gcur[i], hist[i]);
    __syncthreads();
    // scatter records into bucket-ordered staging
#pragma unroll
    for (int j = 0; j < CH / 256; ++j) if (bk[j] >= 0) {
        int p = lstart[bk[j]] + atomicAdd(&lcur[bk[j]], 1);
        ordered[p] = rec[j];
    }
    __syncthreads();
    // copy runs to global: wave-per-bucket, lane-parallel within run
    int w = t >> 6, lane = t & 63;
    for (int b = w; b < NB; b += 4) {
        int n = hist[b];
        if (n) {
            int gp = runbase[b], lp = lstart[b];
            for (int q = lane; q < n; q += 64) esorted[gp + q] = ordered[lp + q];
        }
    }
}

// ---------------- per-node CSR within each bucket segment ----------------
// One block per bucket. All global writes stay inside the block's own
// contiguous segment (or its 1 KB off/cnt slice) -> no cross-XCD ping-pong.

__global__ __launch_bounds__(256) void csr_kernel(const unsigned int* __restrict__ esorted,
                                                  const int* __restrict__ gbase,
                                                  int* __restrict__ off, int* __restrict__ cnt,
                                                  int* __restrict__ esrc, int N, int nbrr) {
    __shared__ int hist[256], lcur[256], tsum[256];
    int b = blockIdx.x;
    int r = b >= nbrr;
    int g = r ? b - nbrr : b;
    int t = threadIdx.x;
    int s0 = gbase[b], s1 = gbase[b + 1];
    hist[t] = 0;
    __syncthreads();
    for (int i = s0 + t; i < s1; i += 256)
        atomicAdd(&hist[(esorted[i] >> 17) & 255], 1);
    __syncthreads();
    int h = hist[t];
    tsum[t] = h; __syncthreads();
    for (int d = 1; d < 256; d <<= 1) {
        int add = (t >= d) ? tsum[t - d] : 0;
        __syncthreads(); tsum[t] += add; __syncthreads();
    }
    int start = tsum[t] - h;   // exclusive
    int node = g * 256 + t;
    if (node < N) { off[r * N + node] = s0 + start; cnt[r * N + node] = h; }
    lcur[t] = start;
    __syncthreads();
    for (int i = s0 + t; i < s1; i += 256) {
        unsigned int rec = esorted[i];
        int tl = (rec >> 17) & 255;
        int p = atomicAdd(&lcur[tl], 1);
        esrc[s0 + p] = rec & 0x1FFFF;
    }
}

// ---------------- gather-reduce into Abig cols 0:255 ----------------
// One half-wave (32 lanes x 8B = 256B = one bf16 row) per (node, relation).
// Edge loop unrolled x8 with clamped indices (MLP); fine-grained 2N grid
// for occupancy (csrgather fusion at NB blocks dropped occupancy to 29%).
__global__ __launch_bounds__(256) void gather_kernel(const int* __restrict__ off,
                                                     const int* __restrict__ cnt,
                                                     const int* __restrict__ esrc,
                                                     uint2* __restrict__ Ab, int N) {
    int hw = blockIdx.x * 8 + (threadIdx.x >> 5);
    int lane = threadIdx.x & 31;
    if (hw >= 2 * N) return;
    int r = (hw >= N);
    int n = r ? hw - N : hw;
    int s0 = off[hw], c = cnt[hw];
    float a0 = 0.f, a1 = 0.f, a2 = 0.f, a3 = 0.f;
    for (int i0 = 0; i0 < c; i0 += 8) {
        int cm1 = c - 1;
        int s[8]; uint2 v[8];
#pragma unroll
        for (int u = 0; u < 8; ++u) {
            int j = i0 + u; j = (j <= cm1) ? j : cm1;
            s[u] = esrc[s0 + j];
        }
#pragma unroll
        for (int u = 0; u < 8; ++u)
            v[u] = Ab[(size_t)s[u] * 96 + 64 + lane];
#pragma unroll
        for (int u = 0; u < 8; ++u) {
            if (i0 + u < c) {
                a0 += BFLO(v[u].x); a1 += BFHI(v[u].x);
                a2 += BFLO(v[u].y); a3 += BFHI(v[u].y);
            }
        }
    }
    union { uint2 u; bf16 h[4]; } o;
    o.h[0] = __float2bfloat16(a0); o.h[1] = __float2bfloat16(a1);
    o.h[2] = __float2bfloat16(a2); o.h[3] = __float2bfloat16(a3);
    Ab[(size_t)n * 96 + (size_t)r * 32 + lane] = o.u;
}

// ---------------- GEMM1: agg[M,128](bf16) = Abig @ B1T^T,  K = 384 ----------------

__global__ __launch_bounds__(256) void gemm1_kernel(const bf16* __restrict__ Ab,
                                                    const bf16* __restrict__ B1T,
                                                    bf16* __restrict__ agg, int M) {
    __shared__ bf16 Al[128 * 72];
    __shared__ bf16 Bl[128 * 72];
    int t = threadIdx.x;
    int lane = t & 63, wv = t >> 6, wm = wv >> 1, wn = wv & 1;
    int m0 = blockIdx.x * 128;
    v4f acc[4][4] = {};
    for (int kt = 0; kt < 6; ++kt) {
        int k0 = kt * 64;
#pragma unroll
        for (int i = 0; i < 4; ++i) {
            int q = i * 256 + t;
            int row = q >> 3, ch = q & 7;
            int grow = m0 + row;
            int4 va = {0, 0, 0, 0};
            if (grow < M) va = *(const int4*)(Ab + (size_t)grow * 384 + k0 + ch * 8);
            *(int4*)&Al[row * 72 + ch * 8] = va;
            *(int4*)&Bl[row * 72 + ch * 8] = *(const int4*)(B1T + row * 384 + k0 + ch * 8);
        }
        __syncthreads();
        int r = lane & 15, qq = lane >> 4;
#pragma unroll
        for (int ks = 0; ks < 2; ++ks) {
            v8s af[4], bfr[4];
#pragma unroll
            for (int tm = 0; tm < 4; ++tm)
                af[tm] = *(const v8s*)&Al[(wm * 64 + tm * 16 + r) * 72 + ks * 32 + qq * 8];
#pragma unroll
            for (int tn = 0; tn < 4; ++tn)
                bfr[tn] = *(const v8s*)&Bl[(wn * 64 + tn * 16 + r) * 72 + ks * 32 + qq * 8];
#pragma unroll
            for (int tm = 0; tm < 4; ++tm)
#pragma unroll
                for (int tn = 0; tn < 4; ++tn)
                    acc[tm][tn] = __builtin_amdgcn_mfma_f32_16x16x32_bf16(af[tm], bfr[tn], acc[tm][tn], 0, 0, 0);
        }
        __syncthreads();
    }
    int r = lane & 15, qq = lane >> 4;
#pragma unroll
    for (int tm = 0; tm < 4; ++tm)
#pragma unroll
        for (int tn = 0; tn < 4; ++tn)
#pragma unroll
            for (int reg = 0; reg < 4; ++reg) {
                int grow = m0 + wm * 64 + tm * 16 + qq * 4 + reg;
                if (grow < M) {
                    int col = wn * 64 + tn * 16 + r;
                    agg[(size_t)grow * 128 + col] = __float2bfloat16(acc[tm][tn][reg]);
                }
            }
}

// ---------------- GEMM2: out[n](fp32) = relu(b + sum_kk agg[n+kk-1] @ Wkk^T),  K = 384 ----------------

__global__ __launch_bounds__(256) void gemm2_kernel(const bf16* __restrict__ agg,
                                                    const bf16* __restrict__ B2T,
                                                    const float* __restrict__ cbf,
                                                    float* __restrict__ out, int M) {
    __shared__ bf16 Al[128 * 72];
    __shared__ bf16 Bl[128 * 72];
    int t = threadIdx.x;
    int lane = t & 63, wv = t >> 6, wm = wv >> 1, wn = wv & 1;
    int m0 = blockIdx.x * 128;
    v4f acc[4][4] = {};
    for (int kt = 0; kt < 6; ++kt) {
        int k0 = kt * 64;
        int kk = k0 >> 7;          // which conv tap (0..2)
        int rem = k0 & 127;        // ci offset within tap
#pragma unroll
        for (int i = 0; i < 4; ++i) {
            int q = i * 256 + t;
            int row = q >> 3, ch = q & 7;
            int srow = m0 + row + kk - 1;
            int4 va = {0, 0, 0, 0};
            if (srow >= 0 && srow < M) {
                va = *(const int4*)(agg + (size_t)srow * 128 + rem + ch * 8);
            }
            *(int4*)&Al[row * 72 + ch * 8] = va;
            *(int4*)&Bl[row * 72 + ch * 8] = *(const int4*)(B2T + row * 384 + k0 + ch * 8);
        }
        __syncthreads();
        int r = lane & 15, qq = lane >> 4;
#pragma unroll
        for (int ks = 0; ks < 2; ++ks) {
            v8s af[4], bfr[4];
#pragma unroll
            for (int tm = 0; tm < 4; ++tm)
                af[tm] = *(const v8s*)&Al[(wm * 64 + tm * 16 + r) * 72 + ks * 32 + qq * 8];
#pragma unroll
            for (int tn = 0; tn < 4; ++tn)
                bfr[tn] = *(const v8s*)&Bl[(wn * 64 + tn * 16 + r) * 72 + ks * 32 + qq * 8];
#pragma unroll
            for (int tm = 0; tm < 4; ++tm)
#pragma unroll
                for (int tn = 0; tn < 4; ++tn)
                    acc[tm][tn] = __builtin_amdgcn_mfma_f32_16x16x32_bf16(af[tm], bfr[tn], acc[tm][tn], 0, 0, 0);
        }
        __syncthreads();
    }
    int r = lane & 15, qq = lane >> 4;
#pragma unroll
    for (int tm = 0; tm < 4; ++tm)
#pragma unroll
        for (int tn = 0; tn < 4; ++tn) {
            int col = wn * 64 + tn * 16 + r;
            float bias = cbf[col];
#pragma unroll
            for (int reg = 0; reg < 4; ++reg) {
                int grow = m0 + wm * 64 + tm * 16 + qq * 4 + reg;
                if (grow < M) {
                    float v = acc[tm][tn][reg] + bias;
                    out[(size_t)grow * 128 + col] = fmaxf(v, 0.f);
                }
            }
        }
}

// ---------------- launch ----------------

extern "C" void kernel_launch(void* const* d_in, const int* in_sizes, int n_in,
                              void* d_out, int out_size, void* d_ws, size_t ws_size,
                              hipStream_t stream) {
    const float* x     = (const float*)d_in[0];
    const int*   e0    = (const int*)d_in[1];
    const int*   e1    = (const int*)d_in[2];
    const float* Wrel  = (const float*)d_in[3];
    const float* Wself = (const float*)d_in[4];
    const float* convw = (const float*)d_in[5];
    const float* convb = (const float*)d_in[6];
    float* out = (float*)d_out;

    int N = in_sizes[0] / 128;   // 100000
    int E = in_sizes[1] / 2;     // 600000
    int nbrr = (N + 255) >> 8;   // 391 buckets per relation
    int NB = 2 * nbrr;           // 782

    char* p = (char*)d_ws;
    auto alloc = [&](size_t bytes) { char* q = p; p += (bytes + 255) & ~(size_t)255; return q; };
    int*  gcnt  = (int*)alloc((size_t)MAXNB * 4);
    int*  gbase = (int*)alloc((size_t)(MAXNB + 1) * 4);
    int*  gcur  = (int*)alloc((size_t)MAXNB * 4);
    unsigned int* esorted = (unsigned int*)alloc((size_t)2 * E * 4);
    int*  esrc  = (int*)alloc((size_t)2 * E * 4);
    int*  off   = (int*)alloc((size_t)2 * N * 4);
    int*  cnt   = (int*)alloc((size_t)2 * N * 4);
    bf16* Ab   = (bf16*)alloc((size_t)N * 384 * 2);   // [H0 | H1 | x_bf16]
    bf16* agg  = (bf16*)alloc((size_t)N * 128 * 2);
    bf16* B1T  = (bf16*)alloc(384 * 128 * 2);
    bf16* B2T  = (bf16*)alloc(384 * 128 * 2);
    float* cbf = (float*)alloc(512);

    hipMemsetAsync(gcnt, 0, (size_t)NB * 4, stream);

    int cvtBlocks = (N * 32 + 255) / 256;
    int prepBlocks = (98432 + 255) / 256;
    cvtprep_kernel<<<cvtBlocks + prepBlocks, 256, 0, stream>>>((const float4*)x, (uint2*)Ab,
                                                               Wrel, Wself, convw, convb,
                                                               B1T, B2T, cbf, N, cvtBlocks);

    int chBlocks = (2 * E + CH - 1) / CH;    // 147
    count_kernel<<<chBlocks, 256, 0, stream>>>(e0, e1, gcnt, E, nbrr);
    bscan_kernel<<<1, 256, 0, stream>>>(gcnt, gbase, gcur, NB);
    dist_kernel<<<chBlocks, 256, 0, stream>>>(e0, e1, gcur, esorted, E, nbrr);
    csr_kernel<<<NB, 256, 0, stream>>>(esorted, gbase, off, cnt, esrc, N, nbrr);

    gather_kernel<<<(2 * N + 7) / 8, 256, 0, stream>>>(off, cnt, esrc, (uint2*)Ab, N);

    int mBlocks = (N + 127) / 128;
    gemm1_kernel<<<mBlocks, 256, 0, stream>>>(Ab, B1T, agg, N);
    gemm2_kernel<<<mBlocks, 256, 0, stream>>>(agg, B2T, cbf, out, N);
}

// Round 8
// 320.679 us; speedup vs baseline: 1.1045x; 1.0385x over previous
//
#include <hip/hip_runtime.h>
#include <hip/hip_bf16.h>

typedef __hip_bfloat16 bf16;
typedef short v8s __attribute__((ext_vector_type(8)));
typedef float v4f __attribute__((ext_vector_type(4)));

#define BFLO(u) __uint_as_float((u) << 16)
#define BFHI(u) __uint_as_float((u) & 0xffff0000u)

#define CH 4096        // edges per count/distribute block (293 blocks > 256 CUs)
#define MAXNB 800      // >= 2 * ceil(N/256) = 782

// Derive index stride in-block: int64 LE with values < 2^31 has zero odd slots.
__device__ __forceinline__ int block_stride(const int* e0, int E, int* sm) {
    int t = threadIdx.x;
    if (t == 0) *sm = 0;
    __syncthreads();
    int nz = 0;
    for (int i = t; i < 2048; i += 256) {
        int slot = 2 * i + 1;
        if (slot < 2 * E) nz |= (e0[slot] != 0);
    }
    if (nz) atomicOr(sm, 1);
    __syncthreads();
    return *sm ? 1 : 2;
}

// ---------------- fused front: cvt (x->bf16 into Abig) | weight prep | bucket count ----------------

__global__ __launch_bounds__(256) void front_kernel(const float4* __restrict__ x4,
                                                    uint2* __restrict__ Ab,
                                                    const float* __restrict__ Wrel,
                                                    const float* __restrict__ Wself,
                                                    const float* __restrict__ convw,
                                                    const float* __restrict__ convb,
                                                    bf16* __restrict__ B1T,
                                                    bf16* __restrict__ B2T,
                                                    float* __restrict__ cbf,
                                                    const int* __restrict__ e0,
                                                    const int* __restrict__ e1,
                                                    int* __restrict__ gcnt,
                                                    int N, int E, int nbrr,
                                                    int cvtBlocks, int prepBlocks) {
    int b = blockIdx.x;
    if (b < cvtBlocks) {
        int i = b * 256 + threadIdx.x;
        if (i >= N * 32) return;
        int n = i >> 5, g = i & 31;
        float4 f = x4[i];
        union { uint2 u; bf16 h[4]; } o;
        o.h[0] = __float2bfloat16(f.x); o.h[1] = __float2bfloat16(f.y);
        o.h[2] = __float2bfloat16(f.z); o.h[3] = __float2bfloat16(f.w);
        Ab[(size_t)n * 96 + 64 + g] = o.u;
    } else if (b < cvtBlocks + prepBlocks) {
        int i = (b - cvtBlocks) * 256 + threadIdx.x;
        if (i < 49152) {
            int co = i / 384, k = i % 384;
            float v;
            if (k < 128)      v = Wrel[co * 128 + k];
            else if (k < 256) v = Wrel[16384 + co * 128 + (k - 128)];
            else              v = Wself[co * 128 + (k - 256)];
            B1T[i] = __float2bfloat16(v);
        } else if (i < 98304) {
            int j = i - 49152;
            int co = j / 384, k = j % 384, kk = k >> 7, ci = k & 127;
            B2T[j] = __float2bfloat16(convw[co * 384 + ci * 3 + kk]);
        } else if (i < 98432) {
            int c = i - 98304;
            cbf[c] = convb[c];
        }
    } else {
        // ---- bucket count chunk ----
        __shared__ int hist[MAXNB];
        __shared__ int smf;
        int st = block_stride(e0, E, &smf);
        int NB = 2 * nbrr;
        int t = threadIdx.x;
        for (int i = t; i < NB; i += 256) hist[i] = 0;
        __syncthreads();
        long base = (long)(b - cvtBlocks - prepBlocks) * CH;
#pragma unroll
        for (int j = 0; j < CH / 256; ++j) {
            long e = base + j * 256 + t;
            if (e < 2 * (long)E) {
                int r = e >= E;
                long idx = r ? e - E : e;
                int tgt = (r ? e1 : e0)[(size_t)(E + idx) * st];
                atomicAdd(&hist[r * nbrr + (tgt >> 8)], 1);
            }
        }
        __syncthreads();
        for (int i = t; i < NB; i += 256) if (hist[i]) atomicAdd(&gcnt[i], hist[i]);
    }
}

// ---------------- exclusive scan of bucket counts (single block) ----------------

__global__ __launch_bounds__(256) void bscan_kernel(const int* __restrict__ gcnt,
                                                    int* __restrict__ gbase,
                                                    int* __restrict__ gcur, int NB) {
    __shared__ int tsum[256];
    int t = threadIdx.x;
    int v[4]; int s = 0;
#pragma unroll
    for (int j = 0; j < 4; ++j) { int i = t * 4 + j; v[j] = (i < NB) ? gcnt[i] : 0; s += v[j]; }
    tsum[t] = s; __syncthreads();
    for (int d = 1; d < 256; d <<= 1) {
        int add = (t >= d) ? tsum[t - d] : 0;
        __syncthreads(); tsum[t] += add; __syncthreads();
    }
    int run = tsum[t] - s;
#pragma unroll
    for (int j = 0; j < 4; ++j) {
        int i = t * 4 + j;
        if (i < NB) { gbase[i] = run; gcur[i] = run; }
        run += v[j];
    }
    if (t == 255) gbase[NB] = run;
}

// ---------------- distribute: LDS-sorted runs -> contiguous bucket segments ----------------
// record = src (17b) | tgt_local (8b) << 17

__global__ __launch_bounds__(256) void dist_kernel(const int* __restrict__ e0,
                                                   const int* __restrict__ e1,
                                                   int* __restrict__ gcur,
                                                   unsigned int* __restrict__ esorted,
                                                   int E, int nbrr) {
    __shared__ int hist[MAXNB], lstart[MAXNB], lcur[MAXNB], runbase[MAXNB];
    __shared__ unsigned int ordered[CH];
    __shared__ int tsum[256];
    __shared__ int smf;
    int st = block_stride(e0, E, &smf);
    int NB = 2 * nbrr;
    int t = threadIdx.x;
    for (int i = t; i < NB; i += 256) { hist[i] = 0; lcur[i] = 0; }
    __syncthreads();
    long base = (long)blockIdx.x * CH;
    unsigned int rec[CH / 256]; short bk[CH / 256];
#pragma unroll
    for (int j = 0; j < CH / 256; ++j) {
        long e = base + j * 256 + t;
        if (e < 2 * (long)E) {
            int r = e >= E;
            long idx = r ? e - E : e;
            const int* ei = r ? e1 : e0;
            int src = ei[(size_t)idx * st];
            int tgt = ei[(size_t)(E + idx) * st];
            bk[j] = (short)(r * nbrr + (tgt >> 8));
            rec[j] = (unsigned int)src | ((unsigned int)(tgt & 255) << 17);
            atomicAdd(&hist[bk[j]], 1);
        } else bk[j] = -1;
    }
    __syncthreads();
    {   // block-level exclusive scan of hist -> lstart
        int vv[4]; int s = 0;
#pragma unroll
        for (int j = 0; j < 4; ++j) { int i = t * 4 + j; vv[j] = (i < NB) ? hist[i] : 0; s += vv[j]; }
        tsum[t] = s; __syncthreads();
        for (int d = 1; d < 256; d <<= 1) {
            int add = (t >= d) ? tsum[t - d] : 0;
            __syncthreads(); tsum[t] += add; __syncthreads();
        }
        int run = tsum[t] - s;
#pragma unroll
        for (int j = 0; j < 4; ++j) { int i = t * 4 + j; if (i < NB) { lstart[i] = run; run += vv[j]; } }
    }
    __syncthreads();
    // reserve global run per touched bucket
    for (int i = t; i < NB; i += 256) if (hist[i]) runbase[i] = atomicAdd(&gcur[i], hist[i]);
    __syncthreads();
    // scatter records into bucket-ordered staging
#pragma unroll
    for (int j = 0; j < CH / 256; ++j) if (bk[j] >= 0) {
        int p = lstart[bk[j]] + atomicAdd(&lcur[bk[j]], 1);
        ordered[p] = rec[j];
    }
    __syncthreads();
    // copy runs to global: wave-per-bucket, lane-parallel within run
    int w = t >> 6, lane = t & 63;
    for (int b = w; b < NB; b += 4) {
        int n = hist[b];
        if (n) {
            int gp = runbase[b], lp = lstart[b];
            for (int q = lane; q < n; q += 64) esorted[gp + q] = ordered[lp + q];
        }
    }
}

// ---------------- per-node CSR within each bucket segment ----------------
// One block per bucket. All global writes stay inside the block's own
// contiguous segment (or its 1 KB off/cnt slice) -> no cross-XCD ping-pong.

__global__ __launch_bounds__(256) void csr_kernel(const unsigned int* __restrict__ esorted,
                                                  const int* __restrict__ gbase,
                                                  int* __restrict__ off, int* __restrict__ cnt,
                                                  int* __restrict__ esrc, int N, int nbrr) {
    __shared__ int hist[256], lcur[256], tsum[256];
    int b = blockIdx.x;
    int r = b >= nbrr;
    int g = r ? b - nbrr : b;
    int t = threadIdx.x;
    int s0 = gbase[b], s1 = gbase[b + 1];
    hist[t] = 0;
    __syncthreads();
    for (int i = s0 + t; i < s1; i += 256)
        atomicAdd(&hist[(esorted[i] >> 17) & 255], 1);
    __syncthreads();
    int h = hist[t];
    tsum[t] = h; __syncthreads();
    for (int d = 1; d < 256; d <<= 1) {
        int add = (t >= d) ? tsum[t - d] : 0;
        __syncthreads(); tsum[t] += add; __syncthreads();
    }
    int start = tsum[t] - h;   // exclusive
    int node = g * 256 + t;
    if (node < N) { off[r * N + node] = s0 + start; cnt[r * N + node] = h; }
    lcur[t] = start;
    __syncthreads();
    for (int i = s0 + t; i < s1; i += 256) {
        unsigned int rec = esorted[i];
        int tl = (rec >> 17) & 255;
        int p = atomicAdd(&lcur[tl], 1);
        esrc[s0 + p] = rec & 0x1FFFF;
    }
}

// ---------------- gather-reduce into Abig cols 0:255 ----------------
// One half-wave (32 lanes x 8B = 256B = one bf16 row) per (node, relation).
// Edge loop unrolled x8 with clamped indices (MLP); fine-grained 2N grid
// for occupancy (csrgather fusion at NB blocks dropped occupancy to 29%).
__global__ __launch_bounds__(256) void gather_kernel(const int* __restrict__ off,
                                                     const int* __restrict__ cnt,
                                                     const int* __restrict__ esrc,
                                                     uint2* __restrict__ Ab, int N) {
    int hw = blockIdx.x * 8 + (threadIdx.x >> 5);
    int lane = threadIdx.x & 31;
    if (hw >= 2 * N) return;
    int r = (hw >= N);
    int n = r ? hw - N : hw;
    int s0 = off[hw], c = cnt[hw];
    float a0 = 0.f, a1 = 0.f, a2 = 0.f, a3 = 0.f;
    for (int i0 = 0; i0 < c; i0 += 8) {
        int cm1 = c - 1;
        int s[8]; uint2 v[8];
#pragma unroll
        for (int u = 0; u < 8; ++u) {
            int j = i0 + u; j = (j <= cm1) ? j : cm1;
            s[u] = esrc[s0 + j];
        }
#pragma unroll
        for (int u = 0; u < 8; ++u)
            v[u] = Ab[(size_t)s[u] * 96 + 64 + lane];
#pragma unroll
        for (int u = 0; u < 8; ++u) {
            if (i0 + u < c) {
                a0 += BFLO(v[u].x); a1 += BFHI(v[u].x);
                a2 += BFLO(v[u].y); a3 += BFHI(v[u].y);
            }
        }
    }
    union { uint2 u; bf16 h[4]; } o;
    o.h[0] = __float2bfloat16(a0); o.h[1] = __float2bfloat16(a1);
    o.h[2] = __float2bfloat16(a2); o.h[3] = __float2bfloat16(a3);
    Ab[(size_t)n * 96 + (size_t)r * 32 + lane] = o.u;
}

// ---------------- GEMM1: agg[M,128](bf16) = Abig @ B1T^T,  K = 384 ----------------

__global__ __launch_bounds__(256) void gemm1_kernel(const bf16* __restrict__ Ab,
                                                    const bf16* __restrict__ B1T,
                                                    bf16* __restrict__ agg, int M) {
    __shared__ bf16 Al[128 * 72];
    __shared__ bf16 Bl[128 * 72];
    int t = threadIdx.x;
    int lane = t & 63, wv = t >> 6, wm = wv >> 1, wn = wv & 1;
    int m0 = blockIdx.x * 128;
    v4f acc[4][4] = {};
    for (int kt = 0; kt < 6; ++kt) {
        int k0 = kt * 64;
#pragma unroll
        for (int i = 0; i < 4; ++i) {
            int q = i * 256 + t;
            int row = q >> 3, ch = q & 7;
            int grow = m0 + row;
            int4 va = {0, 0, 0, 0};
            if (grow < M) va = *(const int4*)(Ab + (size_t)grow * 384 + k0 + ch * 8);
            *(int4*)&Al[row * 72 + ch * 8] = va;
            *(int4*)&Bl[row * 72 + ch * 8] = *(const int4*)(B1T + row * 384 + k0 + ch * 8);
        }
        __syncthreads();
        int r = lane & 15, qq = lane >> 4;
#pragma unroll
        for (int ks = 0; ks < 2; ++ks) {
            v8s af[4], bfr[4];
#pragma unroll
            for (int tm = 0; tm < 4; ++tm)
                af[tm] = *(const v8s*)&Al[(wm * 64 + tm * 16 + r) * 72 + ks * 32 + qq * 8];
#pragma unroll
            for (int tn = 0; tn < 4; ++tn)
                bfr[tn] = *(const v8s*)&Bl[(wn * 64 + tn * 16 + r) * 72 + ks * 32 + qq * 8];
#pragma unroll
            for (int tm = 0; tm < 4; ++tm)
#pragma unroll
                for (int tn = 0; tn < 4; ++tn)
                    acc[tm][tn] = __builtin_amdgcn_mfma_f32_16x16x32_bf16(af[tm], bfr[tn], acc[tm][tn], 0, 0, 0);
        }
        __syncthreads();
    }
    int r = lane & 15, qq = lane >> 4;
#pragma unroll
    for (int tm = 0; tm < 4; ++tm)
#pragma unroll
        for (int tn = 0; tn < 4; ++tn)
#pragma unroll
            for (int reg = 0; reg < 4; ++reg) {
                int grow = m0 + wm * 64 + tm * 16 + qq * 4 + reg;
                if (grow < M) {
                    int col = wn * 64 + tn * 16 + r;
                    agg[(size_t)grow * 128 + col] = __float2bfloat16(acc[tm][tn][reg]);
                }
            }
}

// ---------------- GEMM2: out[n](fp32) = relu(b + sum_kk agg[n+kk-1] @ Wkk^T),  K = 384 ----------------

__global__ __launch_bounds__(256) void gemm2_kernel(const bf16* __restrict__ agg,
                                                    const bf16* __restrict__ B2T,
                                                    const float* __restrict__ cbf,
                                                    float* __restrict__ out, int M) {
    __shared__ bf16 Al[128 * 72];
    __shared__ bf16 Bl[128 * 72];
    int t = threadIdx.x;
    int lane = t & 63, wv = t >> 6, wm = wv >> 1, wn = wv & 1;
    int m0 = blockIdx.x * 128;
    v4f acc[4][4] = {};
    for (int kt = 0; kt < 6; ++kt) {
        int k0 = kt * 64;
        int kk = k0 >> 7;          // which conv tap (0..2)
        int rem = k0 & 127;        // ci offset within tap
#pragma unroll
        for (int i = 0; i < 4; ++i) {
            int q = i * 256 + t;
            int row = q >> 3, ch = q & 7;
            int srow = m0 + row + kk - 1;
            int4 va = {0, 0, 0, 0};
            if (srow >= 0 && srow < M) {
                va = *(const int4*)(agg + (size_t)srow * 128 + rem + ch * 8);
            }
            *(int4*)&Al[row * 72 + ch * 8] = va;
            *(int4*)&Bl[row * 72 + ch * 8] = *(const int4*)(B2T + row * 384 + k0 + ch * 8);
        }
        __syncthreads();
        int r = lane & 15, qq = lane >> 4;
#pragma unroll
        for (int ks = 0; ks < 2; ++ks) {
            v8s af[4], bfr[4];
#pragma unroll
            for (int tm = 0; tm < 4; ++tm)
                af[tm] = *(const v8s*)&Al[(wm * 64 + tm * 16 + r) * 72 + ks * 32 + qq * 8];
#pragma unroll
            for (int tn = 0; tn < 4; ++tn)
                bfr[tn] = *(const v8s*)&Bl[(wn * 64 + tn * 16 + r) * 72 + ks * 32 + qq * 8];
#pragma unroll
            for (int tm = 0; tm < 4; ++tm)
#pragma unroll
                for (int tn = 0; tn < 4; ++tn)
                    acc[tm][tn] = __builtin_amdgcn_mfma_f32_16x16x32_bf16(af[tm], bfr[tn], acc[tm][tn], 0, 0, 0);
        }
        __syncthreads();
    }
    int r = lane & 15, qq = lane >> 4;
#pragma unroll
    for (int tm = 0; tm < 4; ++tm)
#pragma unroll
        for (int tn = 0; tn < 4; ++tn) {
            int col = wn * 64 + tn * 16 + r;
            float bias = cbf[col];
#pragma unroll
            for (int reg = 0; reg < 4; ++reg) {
                int grow = m0 + wm * 64 + tm * 16 + qq * 4 + reg;
                if (grow < M) {
                    float v = acc[tm][tn][reg] + bias;
                    out[(size_t)grow * 128 + col] = fmaxf(v, 0.f);
                }
            }
        }
}

// ---------------- launch ----------------

extern "C" void kernel_launch(void* const* d_in, const int* in_sizes, int n_in,
                              void* d_out, int out_size, void* d_ws, size_t ws_size,
                              hipStream_t stream) {
    const float* x     = (const float*)d_in[0];
    const int*   e0    = (const int*)d_in[1];
    const int*   e1    = (const int*)d_in[2];
    const float* Wrel  = (const float*)d_in[3];
    const float* Wself = (const float*)d_in[4];
    const float* convw = (const float*)d_in[5];
    const float* convb = (const float*)d_in[6];
    float* out = (float*)d_out;

    int N = in_sizes[0] / 128;   // 100000
    int E = in_sizes[1] / 2;     // 600000
    int nbrr = (N + 255) >> 8;   // 391 buckets per relation
    int NB = 2 * nbrr;           // 782

    char* p = (char*)d_ws;
    auto alloc = [&](size_t bytes) { char* q = p; p += (bytes + 255) & ~(size_t)255; return q; };
    int*  gcnt  = (int*)alloc((size_t)MAXNB * 4);
    int*  gbase = (int*)alloc((size_t)(MAXNB + 1) * 4);
    int*  gcur  = (int*)alloc((size_t)MAXNB * 4);
    unsigned int* esorted = (unsigned int*)alloc((size_t)2 * E * 4);
    int*  esrc  = (int*)alloc((size_t)2 * E * 4);
    int*  off   = (int*)alloc((size_t)2 * N * 4);
    int*  cnt   = (int*)alloc((size_t)2 * N * 4);
    bf16* Ab   = (bf16*)alloc((size_t)N * 384 * 2);   // [H0 | H1 | x_bf16]
    bf16* agg  = (bf16*)alloc((size_t)N * 128 * 2);
    bf16* B1T  = (bf16*)alloc(384 * 128 * 2);
    bf16* B2T  = (bf16*)alloc(384 * 128 * 2);
    float* cbf = (float*)alloc(512);

    hipMemsetAsync(gcnt, 0, (size_t)NB * 4, stream);

    int cvtBlocks = (N * 32 + 255) / 256;       // 12500
    int prepBlocks = (98432 + 255) / 256;       // 385
    int chBlocks = (2 * E + CH - 1) / CH;       // 293
    front_kernel<<<cvtBlocks + prepBlocks + chBlocks, 256, 0, stream>>>(
        (const float4*)x, (uint2*)Ab, Wrel, Wself, convw, convb,
        B1T, B2T, cbf, e0, e1, gcnt, N, E, nbrr, cvtBlocks, prepBlocks);

    bscan_kernel<<<1, 256, 0, stream>>>(gcnt, gbase, gcur, NB);
    dist_kernel<<<chBlocks, 256, 0, stream>>>(e0, e1, gcur, esorted, E, nbrr);
    csr_kernel<<<NB, 256, 0, stream>>>(esorted, gbase, off, cnt, esrc, N, nbrr);

    gather_kernel<<<(2 * N + 7) / 8, 256, 0, stream>>>(off, cnt, esrc, (uint2*)Ab, N);

    int mBlocks = (N + 127) / 128;
    gemm1_kernel<<<mBlocks, 256, 0, stream>>>(Ab, B1T, agg, N);
    gemm2_kernel<<<mBlocks, 256, 0, stream>>>(agg, B2T, cbf, out, N);
}

// Round 9
// 307.594 us; speedup vs baseline: 1.1515x; 1.0425x over previous
//
#include <hip/hip_runtime.h>
#include <hip/hip_bf16.h>

typedef __hip_bfloat16 bf16;
typedef short v8s __attribute__((ext_vector_type(8)));
typedef float v4f __attribute__((ext_vector_type(4)));

#define BFLO(u) __uint_as_float((u) << 16)
#define BFHI(u) __uint_as_float((u) & 0xffff0000u)

#define CH 4096        // edges per count/distribute block (293 blocks > 256 CUs)
#define MAXNB 800      // >= 2 * ceil(N/256) = 782

// Derive index stride in-block: int64 LE with values < 2^31 has zero odd slots.
__device__ __forceinline__ int block_stride(const int* e0, int E, int* sm) {
    int t = threadIdx.x;
    if (t == 0) *sm = 0;
    __syncthreads();
    int nz = 0;
    for (int i = t; i < 2048; i += 256) {
        int slot = 2 * i + 1;
        if (slot < 2 * E) nz |= (e0[slot] != 0);
    }
    if (nz) atomicOr(sm, 1);
    __syncthreads();
    return *sm ? 1 : 2;
}

// ---------------- fused front: cvt (x->bf16 into Abig) | weight prep | bucket count ----------------

__global__ __launch_bounds__(256) void front_kernel(const float4* __restrict__ x4,
                                                    uint2* __restrict__ Ab,
                                                    const float* __restrict__ Wrel,
                                                    const float* __restrict__ Wself,
                                                    const float* __restrict__ convw,
                                                    const float* __restrict__ convb,
                                                    bf16* __restrict__ B1T,
                                                    bf16* __restrict__ B2T,
                                                    float* __restrict__ cbf,
                                                    const int* __restrict__ e0,
                                                    const int* __restrict__ e1,
                                                    int* __restrict__ gcnt,
                                                    int N, int E, int nbrr,
                                                    int cvtBlocks, int prepBlocks) {
    int b = blockIdx.x;
    if (b < cvtBlocks) {
        int i = b * 256 + threadIdx.x;
        if (i >= N * 32) return;
        int n = i >> 5, g = i & 31;
        float4 f = x4[i];
        union { uint2 u; bf16 h[4]; } o;
        o.h[0] = __float2bfloat16(f.x); o.h[1] = __float2bfloat16(f.y);
        o.h[2] = __float2bfloat16(f.z); o.h[3] = __float2bfloat16(f.w);
        Ab[(size_t)n * 96 + 64 + g] = o.u;
    } else if (b < cvtBlocks + prepBlocks) {
        int i = (b - cvtBlocks) * 256 + threadIdx.x;
        if (i < 49152) {
            int co = i / 384, k = i % 384;
            float v;
            if (k < 128)      v = Wrel[co * 128 + k];
            else if (k < 256) v = Wrel[16384 + co * 128 + (k - 128)];
            else              v = Wself[co * 128 + (k - 256)];
            B1T[i] = __float2bfloat16(v);
        } else if (i < 98304) {
            int j = i - 49152;
            int co = j / 384, k = j % 384, kk = k >> 7, ci = k & 127;
            B2T[j] = __float2bfloat16(convw[co * 384 + ci * 3 + kk]);
        } else if (i < 98432) {
            int c = i - 98304;
            cbf[c] = convb[c];
        }
    } else {
        // ---- bucket count chunk ----
        __shared__ int hist[MAXNB];
        __shared__ int smf;
        int st = block_stride(e0, E, &smf);
        int NB = 2 * nbrr;
        int t = threadIdx.x;
        for (int i = t; i < NB; i += 256) hist[i] = 0;
        __syncthreads();
        long base = (long)(b - cvtBlocks - prepBlocks) * CH;
#pragma unroll
        for (int j = 0; j < CH / 256; ++j) {
            long e = base + j * 256 + t;
            if (e < 2 * (long)E) {
                int r = e >= E;
                long idx = r ? e - E : e;
                int tgt = (r ? e1 : e0)[(size_t)(E + idx) * st];
                atomicAdd(&hist[r * nbrr + (tgt >> 8)], 1);
            }
        }
        __syncthreads();
        for (int i = t; i < NB; i += 256) if (hist[i]) atomicAdd(&gcnt[i], hist[i]);
    }
}

// ---------------- exclusive scan of bucket counts (single block) ----------------

__global__ __launch_bounds__(256) void bscan_kernel(const int* __restrict__ gcnt,
                                                    int* __restrict__ gbase,
                                                    int* __restrict__ gcur, int NB) {
    __shared__ int tsum[256];
    int t = threadIdx.x;
    int v[4]; int s = 0;
#pragma unroll
    for (int j = 0; j < 4; ++j) { int i = t * 4 + j; v[j] = (i < NB) ? gcnt[i] : 0; s += v[j]; }
    tsum[t] = s; __syncthreads();
    for (int d = 1; d < 256; d <<= 1) {
        int add = (t >= d) ? tsum[t - d] : 0;
        __syncthreads(); tsum[t] += add; __syncthreads();
    }
    int run = tsum[t] - s;
#pragma unroll
    for (int j = 0; j < 4; ++j) {
        int i = t * 4 + j;
        if (i < NB) { gbase[i] = run; gcur[i] = run; }
        run += v[j];
    }
    if (t == 255) gbase[NB] = run;
}

// ---------------- distribute: LDS-sorted runs -> contiguous bucket segments ----------------
// record = src (17b) | tgt_local (8b) << 17

__global__ __launch_bounds__(256) void dist_kernel(const int* __restrict__ e0,
                                                   const int* __restrict__ e1,
                                                   int* __restrict__ gcur,
                                                   unsigned int* __restrict__ esorted,
                                                   int E, int nbrr) {
    __shared__ int hist[MAXNB], lstart[MAXNB], lcur[MAXNB], runbase[MAXNB];
    __shared__ unsigned int ordered[CH];
    __shared__ int tsum[256];
    __shared__ int smf;
    int st = block_stride(e0, E, &smf);
    int NB = 2 * nbrr;
    int t = threadIdx.x;
    for (int i = t; i < NB; i += 256) { hist[i] = 0; lcur[i] = 0; }
    __syncthreads();
    long base = (long)blockIdx.x * CH;
    unsigned int rec[CH / 256]; short bk[CH / 256];
#pragma unroll
    for (int j = 0; j < CH / 256; ++j) {
        long e = base + j * 256 + t;
        if (e < 2 * (long)E) {
            int r = e >= E;
            long idx = r ? e - E : e;
            const int* ei = r ? e1 : e0;
            int src = ei[(size_t)idx * st];
            int tgt = ei[(size_t)(E + idx) * st];
            bk[j] = (short)(r * nbrr + (tgt >> 8));
            rec[j] = (unsigned int)src | ((unsigned int)(tgt & 255) << 17);
            atomicAdd(&hist[bk[j]], 1);
        } else bk[j] = -1;
    }
    __syncthreads();
    {   // block-level exclusive scan of hist -> lstart
        int vv[4]; int s = 0;
#pragma unroll
        for (int j = 0; j < 4; ++j) { int i = t * 4 + j; vv[j] = (i < NB) ? hist[i] : 0; s += vv[j]; }
        tsum[t] = s; __syncthreads();
        for (int d = 1; d < 256; d <<= 1) {
            int add = (t >= d) ? tsum[t - d] : 0;
            __syncthreads(); tsum[t] += add; __syncthreads();
        }
        int run = tsum[t] - s;
#pragma unroll
        for (int j = 0; j < 4; ++j) { int i = t * 4 + j; if (i < NB) { lstart[i] = run; run += vv[j]; } }
    }
    __syncthreads();
    // reserve global run per touched bucket
    for (int i = t; i < NB; i += 256) if (hist[i]) runbase[i] = atomicAdd(&gcur[i], hist[i]);
    __syncthreads();
    // scatter records into bucket-ordered staging
#pragma unroll
    for (int j = 0; j < CH / 256; ++j) if (bk[j] >= 0) {
        int p = lstart[bk[j]] + atomicAdd(&lcur[bk[j]], 1);
        ordered[p] = rec[j];
    }
    __syncthreads();
    // copy runs to global: wave-per-bucket, lane-parallel within run
    int w = t >> 6, lane = t & 63;
    for (int b = w; b < NB; b += 4) {
        int n = hist[b];
        if (n) {
            int gp = runbase[b], lp = lstart[b];
            for (int q = lane; q < n; q += 64) esorted[gp + q] = ordered[lp + q];
        }
    }
}

// ---------------- per-node CSR within each bucket segment ----------------

__global__ __launch_bounds__(256) void csr_kernel(const unsigned int* __restrict__ esorted,
                                                  const int* __restrict__ gbase,
                                                  int* __restrict__ off, int* __restrict__ cnt,
                                                  int* __restrict__ esrc, int N, int nbrr) {
    __shared__ int hist[256], lcur[256], tsum[256];
    int b = blockIdx.x;
    int r = b >= nbrr;
    int g = r ? b - nbrr : b;
    int t = threadIdx.x;
    int s0 = gbase[b], s1 = gbase[b + 1];
    hist[t] = 0;
    __syncthreads();
    for (int i = s0 + t; i < s1; i += 256)
        atomicAdd(&hist[(esorted[i] >> 17) & 255], 1);
    __syncthreads();
    int h = hist[t];
    tsum[t] = h; __syncthreads();
    for (int d = 1; d < 256; d <<= 1) {
        int add = (t >= d) ? tsum[t - d] : 0;
        __syncthreads(); tsum[t] += add; __syncthreads();
    }
    int start = tsum[t] - h;   // exclusive
    int node = g * 256 + t;
    if (node < N) { off[r * N + node] = s0 + start; cnt[r * N + node] = h; }
    lcur[t] = start;
    __syncthreads();
    for (int i = s0 + t; i < s1; i += 256) {
        unsigned int rec = esorted[i];
        int tl = (rec >> 17) & 255;
        int p = atomicAdd(&lcur[tl], 1);
        esrc[s0 + p] = rec & 0x1FFFF;
    }
}

// ---------------- gather-reduce into Abig cols 0:255 ----------------
// One 16-lane group (16 x 16B = 256B = one bf16 row) per (node, relation).
// uint4 loads halve instruction count vs uint2; unroll-8 -> 32 rows in
// flight per wave.
__global__ __launch_bounds__(256) void gather_kernel(const int* __restrict__ off,
                                                     const int* __restrict__ cnt,
                                                     const int* __restrict__ esrc,
                                                     uint4* __restrict__ Ab4, int N) {
    int grp = blockIdx.x * 16 + (threadIdx.x >> 4);
    int lane = threadIdx.x & 15;
    if (grp >= 2 * N) return;
    int r = (grp >= N);
    int n = r ? grp - N : grp;
    int s0 = off[grp], c = cnt[grp];
    float a0 = 0.f, a1 = 0.f, a2 = 0.f, a3 = 0.f, a4 = 0.f, a5 = 0.f, a6 = 0.f, a7 = 0.f;
    for (int i0 = 0; i0 < c; i0 += 8) {
        int cm1 = c - 1;
        int s[8]; uint4 v[8];
#pragma unroll
        for (int u = 0; u < 8; ++u) {
            int j = i0 + u; j = (j <= cm1) ? j : cm1;
            s[u] = esrc[s0 + j];
        }
#pragma unroll
        for (int u = 0; u < 8; ++u)
            v[u] = Ab4[(size_t)s[u] * 48 + 32 + lane];
#pragma unroll
        for (int u = 0; u < 8; ++u) {
            if (i0 + u < c) {
                a0 += BFLO(v[u].x); a1 += BFHI(v[u].x);
                a2 += BFLO(v[u].y); a3 += BFHI(v[u].y);
                a4 += BFLO(v[u].z); a5 += BFHI(v[u].z);
                a6 += BFLO(v[u].w); a7 += BFHI(v[u].w);
            }
        }
    }
    union { uint4 u; bf16 h[8]; } o;
    o.h[0] = __float2bfloat16(a0); o.h[1] = __float2bfloat16(a1);
    o.h[2] = __float2bfloat16(a2); o.h[3] = __float2bfloat16(a3);
    o.h[4] = __float2bfloat16(a4); o.h[5] = __float2bfloat16(a5);
    o.h[6] = __float2bfloat16(a6); o.h[7] = __float2bfloat16(a7);
    Ab4[(size_t)n * 48 + (size_t)r * 16 + lane] = o.u;
}

// ---------------- fused GEMM1+conv-GEMM2 ----------------
// Per block: compute a 144-row agg tile (rows m0-8 .. m0+135, halo for the
// k=3 conv) into LDS (bf16, stride 136 -> 2-way max bank alias), then the
// conv-GEMM (K = 3 taps x 128) reads A-fragments straight from that tile.
// Kills the agg HBM round-trip (25.6 MB write + 76.8 MB read) and a launch.

__global__ __launch_bounds__(256) void gemm12_kernel(const bf16* __restrict__ Ab,
                                                     const bf16* __restrict__ B1T,
                                                     const bf16* __restrict__ B2T,
                                                     const float* __restrict__ cbf,
                                                     float* __restrict__ out, int M) {
    __shared__ __align__(16) char ldsbuf[57600];
    bf16* agg = (bf16*)ldsbuf;              // 144*136*2 = 39168 B
    bf16* Al  = (bf16*)ldsbuf;              // 144*72*2 = 20736 B (aliases agg; dead before agg writes)
    bf16* Bl  = (bf16*)(ldsbuf + 39168);    // 128*72*2 = 18432 B (phase1 B1T / phase2 B2T chunks)

    int t = threadIdx.x;
    int lane = t & 63, wv = t >> 6;
    int r = lane & 15, qq = lane >> 4;
    int m0 = blockIdx.x * 128;

    // ---- phase 1: agg[144][128] = Ab[m0-8 .. m0+136) @ B1T^T ----
    v4f acc[9][2] = {};
    for (int kt = 0; kt < 6; ++kt) {
        int k0 = kt * 64;
#pragma unroll
        for (int i = 0; i < 9; ++i) {
            int q = i * 256 + t;
            if (q < 1152) {            // A chunk: 144 rows x 8 chunks
                int row = q >> 3, ch = q & 7;
                int ar = m0 - 8 + row;
                int4 va = {0, 0, 0, 0};
                if (ar >= 0 && ar < M) va = *(const int4*)(Ab + (size_t)ar * 384 + k0 + ch * 8);
                *(int4*)&Al[row * 72 + ch * 8] = va;
            } else if (q < 2176) {     // B chunk: 128 rows x 8 chunks
                int j = q - 1152;
                int row = j >> 3, ch = j & 7;
                *(int4*)&Bl[row * 72 + ch * 8] = *(const int4*)(B1T + row * 384 + k0 + ch * 8);
            }
        }
        __syncthreads();
#pragma unroll
        for (int ks = 0; ks < 2; ++ks) {
            v8s bfr[2];
#pragma unroll
            for (int tn = 0; tn < 2; ++tn)
                bfr[tn] = *(const v8s*)&Bl[(wv * 32 + tn * 16 + r) * 72 + ks * 32 + qq * 8];
#pragma unroll
            for (int tm = 0; tm < 9; ++tm) {
                v8s af = *(const v8s*)&Al[(tm * 16 + r) * 72 + ks * 32 + qq * 8];
#pragma unroll
                for (int tn = 0; tn < 2; ++tn)
                    acc[tm][tn] = __builtin_amdgcn_mfma_f32_16x16x32_bf16(af, bfr[tn], acc[tm][tn], 0, 0, 0);
            }
        }
        __syncthreads();
    }
    // write agg tile to LDS (bf16): row = tm*16 + qq*4 + reg, col = wv*32 + tn*16 + r
#pragma unroll
    for (int tm = 0; tm < 9; ++tm)
#pragma unroll
        for (int tn = 0; tn < 2; ++tn)
#pragma unroll
            for (int reg = 0; reg < 4; ++reg)
                agg[(tm * 16 + qq * 4 + reg) * 136 + wv * 32 + tn * 16 + r] =
                    __float2bfloat16(acc[tm][tn][reg]);
    __syncthreads();

    // ---- phase 2: out[m0 .. m0+128) = relu(bias + sum_taps aggLDS(shifted) @ B2T^T) ----
    v4f acc2[8][2] = {};
    for (int kt = 0; kt < 6; ++kt) {
        int k0 = kt * 64;
        int kk = k0 >> 7;          // conv tap 0..2
        int rem = k0 & 127;        // ci offset within tap
#pragma unroll
        for (int i = 0; i < 4; ++i) {
            int q = i * 256 + t;
            int row = q >> 3, ch = q & 7;
            *(int4*)&Bl[row * 72 + ch * 8] = *(const int4*)(B2T + row * 384 + k0 + ch * 8);
        }
        __syncthreads();
#pragma unroll
        for (int ks = 0; ks < 2; ++ks) {
            v8s bfr[2];
#pragma unroll
            for (int tn = 0; tn < 2; ++tn)
                bfr[tn] = *(const v8s*)&Bl[(wv * 32 + tn * 16 + r) * 72 + ks * 32 + qq * 8];
#pragma unroll
            for (int tm = 0; tm < 8; ++tm) {
                // out local row l = tm*16 + r needs agg row l + kk + 7
                v8s af = *(const v8s*)&agg[(tm * 16 + r + kk + 7) * 136 + rem + ks * 32 + qq * 8];
#pragma unroll
                for (int tn = 0; tn < 2; ++tn)
                    acc2[tm][tn] = __builtin_amdgcn_mfma_f32_16x16x32_bf16(af, bfr[tn], acc2[tm][tn], 0, 0, 0);
            }
        }
        __syncthreads();
    }
#pragma unroll
    for (int tm = 0; tm < 8; ++tm)
#pragma unroll
        for (int tn = 0; tn < 2; ++tn) {
            int col = wv * 32 + tn * 16 + r;
            float bias = cbf[col];
#pragma unroll
            for (int reg = 0; reg < 4; ++reg) {
                int grow = m0 + tm * 16 + qq * 4 + reg;
                if (grow < M) {
                    float v = acc2[tm][tn][reg] + bias;
                    out[(size_t)grow * 128 + col] = fmaxf(v, 0.f);
                }
            }
        }
}

// ---------------- launch ----------------

extern "C" void kernel_launch(void* const* d_in, const int* in_sizes, int n_in,
                              void* d_out, int out_size, void* d_ws, size_t ws_size,
                              hipStream_t stream) {
    const float* x     = (const float*)d_in[0];
    const int*   e0    = (const int*)d_in[1];
    const int*   e1    = (const int*)d_in[2];
    const float* Wrel  = (const float*)d_in[3];
    const float* Wself = (const float*)d_in[4];
    const float* convw = (const float*)d_in[5];
    const float* convb = (const float*)d_in[6];
    float* out = (float*)d_out;

    int N = in_sizes[0] / 128;   // 100000
    int E = in_sizes[1] / 2;     // 600000
    int nbrr = (N + 255) >> 8;   // 391 buckets per relation
    int NB = 2 * nbrr;           // 782

    char* p = (char*)d_ws;
    auto alloc = [&](size_t bytes) { char* q = p; p += (bytes + 255) & ~(size_t)255; return q; };
    int*  gcnt  = (int*)alloc((size_t)MAXNB * 4);
    int*  gbase = (int*)alloc((size_t)(MAXNB + 1) * 4);
    int*  gcur  = (int*)alloc((size_t)MAXNB * 4);
    unsigned int* esorted = (unsigned int*)alloc((size_t)2 * E * 4);
    int*  esrc  = (int*)alloc((size_t)2 * E * 4);
    int*  off   = (int*)alloc((size_t)2 * N * 4);
    int*  cnt   = (int*)alloc((size_t)2 * N * 4);
    bf16* Ab   = (bf16*)alloc((size_t)N * 384 * 2);   // [H0 | H1 | x_bf16]
    bf16* B1T  = (bf16*)alloc(384 * 128 * 2);
    bf16* B2T  = (bf16*)alloc(384 * 128 * 2);
    float* cbf = (float*)alloc(512);

    hipMemsetAsync(gcnt, 0, (size_t)NB * 4, stream);

    int cvtBlocks = (N * 32 + 255) / 256;       // 12500
    int prepBlocks = (98432 + 255) / 256;       // 385
    int chBlocks = (2 * E + CH - 1) / CH;       // 293
    front_kernel<<<cvtBlocks + prepBlocks + chBlocks, 256, 0, stream>>>(
        (const float4*)x, (uint2*)Ab, Wrel, Wself, convw, convb,
        B1T, B2T, cbf, e0, e1, gcnt, N, E, nbrr, cvtBlocks, prepBlocks);

    bscan_kernel<<<1, 256, 0, stream>>>(gcnt, gbase, gcur, NB);
    dist_kernel<<<chBlocks, 256, 0, stream>>>(e0, e1, gcur, esorted, E, nbrr);
    csr_kernel<<<NB, 256, 0, stream>>>(esorted, gbase, off, cnt, esrc, N, nbrr);

    gather_kernel<<<(2 * N + 15) / 16, 256, 0, stream>>>(off, cnt, esrc, (uint4*)Ab, N);

    int mBlocks = (N + 127) / 128;
    gemm12_kernel<<<mBlocks, 256, 0, stream>>>(Ab, B1T, B2T, cbf, out, N);
}